// Round 15
// baseline (797.530 us; speedup 1.0000x reference)
//
#include <hip/hip_runtime.h>
#include <hip/hip_bf16.h>

#define N_NODES 10000
#define E_EDGES 160000
#define E2 (E_EDGES + N_NODES)
#define D_IN 256
#define H 128
#define HEADS 4
#define HD 512
#define L_LAYERS 16
#define OUT_DIM 1024
#define G_GRAPHS 8
#define EPS 1e-5f
#define SPAD 10016

typedef unsigned short ushort_t;
typedef __attribute__((ext_vector_type(8))) short short8;
typedef __attribute__((ext_vector_type(4))) float f32x4;
typedef __attribute__((ext_vector_type(4))) unsigned u32x4;

__device__ __forceinline__ f32x4 mfma16(short8 a, short8 b, f32x4 c) {
    return __builtin_amdgcn_mfma_f32_16x16x32_bf16(a, b, c, 0, 0, 0);
}
__device__ __forceinline__ unsigned short f2b(float f) {   // f32 -> bf16 bits, RNE
    unsigned u = __float_as_uint(f);
    u += 0x7fffu + ((u >> 16) & 1u);
    return (unsigned short)(u >> 16);
}
__device__ __forceinline__ float b2f(unsigned short b) {
    return __uint_as_float((unsigned)b << 16);
}
__device__ __forceinline__ unsigned pk2(float lo, float hi) {  // 2xf32 -> packed bf16x2
    __hip_bfloat162 p = __float22bfloat162_rn(make_float2(lo, hi));
    return *(unsigned*)&p;
}

// ---------------- setup: CSR build (int32 edges) ----------------
__global__ void k_zero(int* deg, int* cur, unsigned* g, int* hist, int* cur2) {
    int i = blockIdx.x * blockDim.x + threadIdx.x;
    if (i < N_NODES) { deg[i] = 0; cur[i] = 0; }
    if (i < G_GRAPHS * H) g[i] = 0u;
    if (i < 256) { hist[i] = 0; cur2[i] = 0; }
}

__global__ void k_count(const int* ei, int* deg) {
    int e = blockIdx.x * blockDim.x + threadIdx.x;
    if (e >= E2) return;
    int d = (e < E_EDGES) ? ei[E_EDGES + e] : (e - E_EDGES);
    atomicAdd(&deg[d], 1);
}

__global__ void k_scan(const int* deg, int* rs) {   // 1 block x 1024, 10 elems/thread
    __shared__ int s[1024];
    int t = threadIdx.x;
    int base = t * 10;
    int loc[10], run = 0;
    #pragma unroll
    for (int i = 0; i < 10; i++) {
        int idx = base + i;
        int v = (idx < N_NODES) ? deg[idx] : 0;
        loc[i] = run; run += v;
    }
    s[t] = run;
    __syncthreads();
    for (int off = 1; off < 1024; off <<= 1) {
        int xv = (t >= off) ? s[t - off] : 0;
        __syncthreads();
        s[t] += xv;
        __syncthreads();
    }
    int excl = s[t] - run;
    #pragma unroll
    for (int i = 0; i < 10; i++) {
        int idx = base + i;
        if (idx <= N_NODES) rs[idx] = excl + loc[i];
    }
}

__global__ void k_fill(const int* ei, const int* rs, int* cur, int* elist) {
    int e = blockIdx.x * blockDim.x + threadIdx.x;
    if (e >= E2) return;
    int s, d;
    if (e < E_EDGES) { s = ei[e]; d = ei[E_EDGES + e]; }
    else { s = d = e - E_EDGES; }
    int pos = atomicAdd(&cur[d], 1);
    elist[rs[d] + pos] = s;
}

// ---------------- degree sort: perm[] groups similar-degree nodes ----------------
__global__ void k_hist(const int* deg, int* hist) {
    int i = blockIdx.x * blockDim.x + threadIdx.x;
    if (i >= N_NODES) return;
    int b = min(deg[i], 255);
    atomicAdd(&hist[b], 1);
}

__global__ void k_binscan(const int* hist, int* binoff) {   // 1 block x 256
    __shared__ int s[256];
    int t = threadIdx.x;
    int v = hist[t];
    s[t] = v;
    __syncthreads();
    for (int off = 1; off < 256; off <<= 1) {
        int xv = (t >= off) ? s[t - off] : 0;
        __syncthreads();
        s[t] += xv;
        __syncthreads();
    }
    binoff[t] = s[t] - v;                       // exclusive
}

__global__ void k_scatter(const int* deg, const int* binoff, int* cur2, int* perm) {
    int i = blockIdx.x * blockDim.x + threadIdx.x;
    if (i >= N_NODES) return;
    int b = min(deg[i], 255);
    int pos = atomicAdd(&cur2[b], 1);
    perm[binoff[b] + pos] = i;
}

// ---------------- weight preprocessing ----------------
// coalesced: one wave per (l, head, j); lanes split k; shfl tree-reduce
__global__ __launch_bounds__(256) void k_vw(const float* __restrict__ Wsrc,
        const float* __restrict__ Wdst, const float* __restrict__ att_src,
        const float* __restrict__ att_dst, float* __restrict__ vsrc,
        float* __restrict__ vdst) {
    int t = threadIdx.x, w = t >> 6, lane = t & 63;
    int unit = blockIdx.x * 4 + w;          // 8192 units
    int j = unit & 127, head = (unit >> 7) & 3, l = unit >> 9;
    int k2 = lane * 2;
    const float2 ws = *(const float2*)(Wsrc + (size_t)l * H * HD + (size_t)j * HD + head * 128 + k2);
    const float2 wd = *(const float2*)(Wdst + (size_t)l * H * HD + (size_t)j * HD + head * 128 + k2);
    const float2 as = *(const float2*)(att_src + (size_t)l * HEADS * H + head * 128 + k2);
    const float2 ad = *(const float2*)(att_dst + (size_t)l * HEADS * H + head * 128 + k2);
    float p = ws.x * as.x + ws.y * as.y;
    float q = wd.x * ad.x + wd.y * ad.y;
    #pragma unroll
    for (int off = 32; off > 0; off >>= 1) {
        p += __shfl_down(p, off);
        q += __shfl_down(q, off);
    }
    if (lane == 0) {
        vsrc[(size_t)l * HD + head * H + j] = p;
        vdst[(size_t)l * HD + head * H + j] = q;
    }
}

// M[l][h*128+k][o] = sum_c Wsrc[l][k][h*128+c] * Wout[l][h*128+c][o]
__global__ __launch_bounds__(256) void k_mm(const float* __restrict__ Wsrc,
        const float* __restrict__ Wout, float* __restrict__ M) {
    __shared__ float As[32][33];
    __shared__ float Bs[32][128];
    int bid = blockIdx.x;
    int q = bid & 3, hh = (bid >> 2) & 3, l = bid >> 4;
    int t = threadIdx.x;
    int ty = t >> 4, tx = t & 15;
    const float* WsB = Wsrc + (size_t)l * H * HD + (size_t)hh * 128;
    const float* WoB = Wout + (size_t)l * HD * H + (size_t)hh * 128 * H;
    float acc[2][8];
    #pragma unroll
    for (int r = 0; r < 2; r++)
        #pragma unroll
        for (int c = 0; c < 8; c++) acc[r][c] = 0.f;
    for (int kt = 0; kt < 4; kt++) {
        #pragma unroll
        for (int i = 0; i < 4; i++) {
            int lin = i * 256 + t;
            int rr = lin >> 5, cc = lin & 31;
            As[rr][cc] = WsB[(size_t)(q * 32 + rr) * HD + kt * 32 + cc];
        }
        #pragma unroll
        for (int i = 0; i < 16; i++) {
            int lin = i * 256 + t;
            int rr = lin >> 7, cc = lin & 127;
            Bs[rr][cc] = WoB[(size_t)(kt * 32 + rr) * H + cc];
        }
        __syncthreads();
        #pragma unroll
        for (int kk = 0; kk < 32; kk++) {
            float a0 = As[ty * 2][kk], a1 = As[ty * 2 + 1][kk];
            float4 b0 = *(const float4*)&Bs[kk][tx * 8];
            float4 b1 = *(const float4*)&Bs[kk][tx * 8 + 4];
            acc[0][0] += a0 * b0.x; acc[0][1] += a0 * b0.y;
            acc[0][2] += a0 * b0.z; acc[0][3] += a0 * b0.w;
            acc[0][4] += a0 * b1.x; acc[0][5] += a0 * b1.y;
            acc[0][6] += a0 * b1.z; acc[0][7] += a0 * b1.w;
            acc[1][0] += a1 * b0.x; acc[1][1] += a1 * b0.y;
            acc[1][2] += a1 * b0.z; acc[1][3] += a1 * b0.w;
            acc[1][4] += a1 * b1.x; acc[1][5] += a1 * b1.y;
            acc[1][6] += a1 * b1.z; acc[1][7] += a1 * b1.w;
        }
        __syncthreads();
    }
    #pragma unroll
    for (int r = 0; r < 2; r++)
        #pragma unroll
        for (int c = 0; c < 8; c++)
            M[(size_t)l * HD * H + (size_t)(hh * 128 + q * 32 + ty * 2 + r) * H + tx * 8 + c]
                = acc[r][c];
}

// pack M [L][512k][128col] f32 -> hi/lo B-frag layout [L][nt8][ks16][lane64][j8] bf16
__global__ void k_pack_out2(const float* M, ushort_t* Wh, ushort_t* Wl) {
    int idx = blockIdx.x * 256 + threadIdx.x;           // 16*65536 total
    int l = idx >> 16, rem = idx & 65535;
    int k = rem >> 7, col = rem & 127;
    float v = M[(size_t)l * HD * H + (size_t)k * H + col];
    unsigned short hi = f2b(v);
    unsigned short lo = f2b(v - b2f(hi));
    int nt = col >> 4, ks = k >> 5, lhi = (k >> 3) & 3, llo = col & 15, j = k & 7;
    size_t addr = (size_t)l * 65536 + (((size_t)(nt * 16 + ks) * 64) + lhi * 16 + llo) * 8 + j;
    Wh[addr] = hi;
    Wl[addr] = lo;
}

// pack W_in [256k][128col] f32 -> [nt8][ks8][lane64][j8] bf16
__global__ void k_pack_win(const float* W, ushort_t* Wp) {
    int idx = blockIdx.x * 256 + threadIdx.x;           // 32768 total
    int k = idx >> 7, col = idx & 127;
    float v = W[(size_t)k * H + col];
    int nt = col >> 4, ks = k >> 5, lhi = (k >> 3) & 3, llo = col & 15, j = k & 7;
    Wp[(((size_t)(nt * 8 + ks) * 64) + lhi * 16 + llo) * 8 + j] = f2b(v);
}

// ---------------- input layer: MFMA + LN + relu + layer-0 alpha epilogue ----------------
__global__ __launch_bounds__(256) void k_in_mfma(
        const float* __restrict__ x, const ushort_t* __restrict__ WpI,
        const float* __restrict__ b_in, const float* __restrict__ lnw,
        const float* __restrict__ lnb, const float* __restrict__ vs,
        const float* __restrict__ vd, float* __restrict__ as0, float* __restrict__ ad0,
        float* __restrict__ h, ushort_t* __restrict__ hb) {
    __shared__ float part1[4][16], part2[4][16];
    __shared__ float apart[4][8][16];
    int t = threadIdx.x, w = t >> 6, lane = t & 63;
    int row0 = blockIdx.x * 16;
    int ar = lane & 15, ac = (lane >> 4) * 8;
    short8 a[8];
    #pragma unroll
    for (int ks = 0; ks < 8; ks++) {
        const float* xp = x + (size_t)(row0 + ar) * D_IN + ks * 32 + ac;
        float4 xa = *(const float4*)xp;
        float4 xb = *(const float4*)(xp + 4);
        u32x4 u;
        u.x = pk2(xa.x, xa.y); u.y = pk2(xa.z, xa.w);
        u.z = pk2(xb.x, xb.y); u.w = pk2(xb.z, xb.w);
        a[ks] = *(short8*)&u;
    }
    const ushort_t* B0 = WpI + ((size_t)(w * 2 + 0) * 8) * 64 * 8;
    const ushort_t* B1 = WpI + ((size_t)(w * 2 + 1) * 8) * 64 * 8;
    f32x4 c0 = {0.f, 0.f, 0.f, 0.f}, c1 = {0.f, 0.f, 0.f, 0.f};
    #pragma unroll
    for (int ks = 0; ks < 8; ks++) {
        short8 b0 = *(const short8*)(B0 + ((size_t)ks * 64 + lane) * 8);
        short8 b1 = *(const short8*)(B1 + ((size_t)ks * 64 + lane) * 8);
        c0 = mfma16(a[ks], b0, c0);
        c1 = mfma16(a[ks], b1, c1);
    }
    int col0 = w * 32 + ar, col1 = w * 32 + 16 + ar;
    int rb = (lane >> 4) * 4;
    float v0[4], v1[4], y0[4], y1[4];
    #pragma unroll
    for (int r = 0; r < 4; r++) {
        v0[r] = c0[r] + b_in[col0];
        v1[r] = c1[r] + b_in[col1];
        float p1 = v0[r] + v1[r];
        float p2 = v0[r] * v0[r] + v1[r] * v1[r];
        #pragma unroll
        for (int off = 1; off < 16; off <<= 1) {
            p1 += __shfl_xor(p1, off);
            p2 += __shfl_xor(p2, off);
        }
        if (ar == 0) { part1[w][rb + r] = p1; part2[w][rb + r] = p2; }
    }
    __syncthreads();
    #pragma unroll
    for (int r = 0; r < 4; r++) {
        int lr = rb + r;
        int row = row0 + lr;
        float s1 = part1[0][lr] + part1[1][lr] + part1[2][lr] + part1[3][lr];
        float s2 = part2[0][lr] + part2[1][lr] + part2[2][lr] + part2[3][lr];
        float m = s1 * (1.f / 128.f);
        float var = s2 * (1.f / 128.f) - m * m;
        float is = rsqrtf(var + EPS);
        y0[r] = fmaxf((v0[r] - m) * is * lnw[col0] + lnb[col0], 0.f);
        y1[r] = fmaxf((v1[r] - m) * is * lnw[col1] + lnb[col1], 0.f);
        h[(size_t)row * H + col0] = y0[r];
        h[(size_t)row * H + col1] = y1[r];
        hb[(size_t)row * H + col0] = f2b(y0[r]);
        hb[(size_t)row * H + col1] = f2b(y1[r]);
    }
    // layer-0 alpha epilogue
    #pragma unroll
    for (int comp = 0; comp < 8; comp++) {
        float vc0 = (comp < 4) ? vs[comp * H + col0] : vd[(comp - 4) * H + col0];
        float vc1 = (comp < 4) ? vs[comp * H + col1] : vd[(comp - 4) * H + col1];
        float p[4];
        #pragma unroll
        for (int r = 0; r < 4; r++) p[r] = y0[r] * vc0 + y1[r] * vc1;
        #pragma unroll
        for (int off = 1; off < 16; off <<= 1)
            #pragma unroll
            for (int r = 0; r < 4; r++) p[r] += __shfl_xor(p[r], off);
        if (ar == 0)
            #pragma unroll
            for (int r = 0; r < 4; r++) apart[w][comp][rb + r] = p[r];
    }
    __syncthreads();
    if (t < 128) {
        int lr = t >> 3, comp = t & 7;
        float s = apart[0][comp][lr] + apart[1][comp][lr]
                + apart[2][comp][lr] + apart[3][comp][lr];
        int node = row0 + lr;
        if (comp < 4) as0[node * 4 + comp] = s;
        else          ad0[node * 4 + comp - 4] = s;
    }
}

// ---------------- fused T-agg + folded out-GEMM(hi+lo) + LN + next-layer alpha ----------------
// node assignment via degree-sorted perm[] (balances the phase-1 barrier)
#define ACC1(uv, wt) do { \
    acc[0] += (wt) * __uint_as_float((uv).x << 16); \
    acc[1] += (wt) * __uint_as_float((uv).x & 0xffff0000u); \
    acc[2] += (wt) * __uint_as_float((uv).y << 16); \
    acc[3] += (wt) * __uint_as_float((uv).y & 0xffff0000u); \
    acc[4] += (wt) * __uint_as_float((uv).z << 16); \
    acc[5] += (wt) * __uint_as_float((uv).z & 0xffff0000u); \
    acc[6] += (wt) * __uint_as_float((uv).w << 16); \
    acc[7] += (wt) * __uint_as_float((uv).w & 0xffff0000u); \
} while (0)

__global__ __launch_bounds__(512) void k_aggout(
        const ushort_t* __restrict__ hb, const float4* __restrict__ as4,
        const float4* __restrict__ ad4, const int* __restrict__ rs,
        const int* __restrict__ elist, const int* __restrict__ perm,
        const ushort_t* __restrict__ Wh, const ushort_t* __restrict__ Wl,
        const float* __restrict__ bout, const float* __restrict__ lnw,
        const float* __restrict__ lnb, const float* __restrict__ vsn,
        const float* __restrict__ vdn, float* __restrict__ asn,
        float* __restrict__ adn, int doAlpha, float* __restrict__ h,
        ushort_t* __restrict__ hbo, int l) {
    __shared__ ushort_t frag[16 * 64 * 8];      // 16KB
    __shared__ int sl[8][64];
    __shared__ float wl[8][64][4];
    __shared__ float part1[8][16], part2[8][16];
    __shared__ float apart[8][8][16];
    int t = threadIdx.x, w = t >> 6, lane = t & 63;
    int base = blockIdx.x * 16;
    int head = lane >> 4;
    int j8 = (lane & 15) * 8;

    // ---- phase 1: aggregate T for 2 nodes per wave (perm-assigned) ----
    for (int q = 0; q < 2; q++) {
        int r = w * 2 + q;
        int node = perm[base + r];
        int start = rs[node], end = rs[node + 1];
        float4 adv = ad4[node];
        float acc[8];
        #pragma unroll
        for (int i = 0; i < 8; i++) acc[i] = 0.f;
        for (int c0 = start; c0 < end; c0 += 64) {
            int cnt = min(64, end - c0);
            if (lane < cnt) {
                int s = elist[c0 + lane];
                sl[w][lane] = s;
                float4 av = as4[s];
                float l0 = av.x + adv.x, l1 = av.y + adv.y, l2 = av.z + adv.z, l3 = av.w + adv.w;
                l0 = (l0 > 0.f) ? l0 : 0.2f * l0;
                l1 = (l1 > 0.f) ? l1 : 0.2f * l1;
                l2 = (l2 > 0.f) ? l2 : 0.2f * l2;
                l3 = (l3 > 0.f) ? l3 : 0.2f * l3;
                float mx = fmaxf(fmaxf(l0, l1), fmaxf(l2, l3));
                float e0 = expf(l0 - mx), e1 = expf(l1 - mx), e2 = expf(l2 - mx), e3 = expf(l3 - mx);
                float inv = 1.f / (e0 + e1 + e2 + e3);
                wl[w][lane][0] = e0 * inv;
                wl[w][lane][1] = e1 * inv;
                wl[w][lane][2] = e2 * inv;
                wl[w][lane][3] = e3 * inv;
            }
            __asm__ volatile("s_waitcnt lgkmcnt(0)" ::: "memory");
            int j = 0;
            if (cnt >= 4) {
                u32x4 b0, b1, b2, b3;
                float q0, q1, q2, q3;
                {
                    int s0 = sl[w][0], s1 = sl[w][1], s2 = sl[w][2], s3 = sl[w][3];
                    q0 = wl[w][0][head]; q1 = wl[w][1][head];
                    q2 = wl[w][2][head]; q3 = wl[w][3][head];
                    b0 = *(const u32x4*)(hb + (size_t)s0 * H + j8);
                    b1 = *(const u32x4*)(hb + (size_t)s1 * H + j8);
                    b2 = *(const u32x4*)(hb + (size_t)s2 * H + j8);
                    b3 = *(const u32x4*)(hb + (size_t)s3 * H + j8);
                }
                for (j = 4; j + 3 < cnt; j += 4) {
                    int s0 = sl[w][j], s1 = sl[w][j + 1], s2 = sl[w][j + 2], s3 = sl[w][j + 3];
                    u32x4 n0 = *(const u32x4*)(hb + (size_t)s0 * H + j8);
                    u32x4 n1 = *(const u32x4*)(hb + (size_t)s1 * H + j8);
                    u32x4 n2 = *(const u32x4*)(hb + (size_t)s2 * H + j8);
                    u32x4 n3 = *(const u32x4*)(hb + (size_t)s3 * H + j8);
                    float r0 = wl[w][j][head], r1 = wl[w][j + 1][head];
                    float r2 = wl[w][j + 2][head], r3 = wl[w][j + 3][head];
                    ACC1(b0, q0); ACC1(b1, q1); ACC1(b2, q2); ACC1(b3, q3);
                    b0 = n0; q0 = r0; b1 = n1; q1 = r1;
                    b2 = n2; q2 = r2; b3 = n3; q3 = r3;
                }
                ACC1(b0, q0); ACC1(b1, q1); ACC1(b2, q2); ACC1(b3, q3);
            }
            for (; j < cnt; j++) {
                int s = sl[w][j];
                float wt = wl[w][j][head];
                u32x4 uv = *(const u32x4*)(hb + (size_t)s * H + j8);
                ACC1(uv, wt);
            }
        }
        u32x4 o;
        o.x = pk2(acc[0], acc[1]);
        o.y = pk2(acc[2], acc[3]);
        o.z = pk2(acc[4], acc[5]);
        o.w = pk2(acc[6], acc[7]);
        int ksn = head * 4 + ((lane >> 2) & 3);
        int gidx = ((lane & 3) * 16 + r) * 16 + (ksn ^ r);
        *(u32x4*)((char*)frag + gidx * 16) = o;
    }
    __syncthreads();

    // ---- phase 2: out-GEMM 16x128, K=512, B = M_hi + M_lo ----
    const ushort_t* WLh = Wh + (size_t)l * 65536;
    const ushort_t* WLl = Wl + (size_t)l * 65536;
    short8 a[16];
    #pragma unroll
    for (int ks = 0; ks < 16; ks++) {
        int gidx = lane * 16 + (ks ^ (lane & 15));
        a[ks] = *(const short8*)((const char*)frag + gidx * 16);
    }
    int ar = lane & 15;
    f32x4 c = {0.f, 0.f, 0.f, 0.f};
    #pragma unroll
    for (int ks = 0; ks < 16; ks++) {
        short8 bh = *(const short8*)(WLh + ((size_t)(w * 16 + ks) * 64 + lane) * 8);
        c = mfma16(a[ks], bh, c);
    }
    #pragma unroll
    for (int ks = 0; ks < 16; ks++) {
        short8 bl = *(const short8*)(WLl + ((size_t)(w * 16 + ks) * 64 + lane) * 8);
        c = mfma16(a[ks], bl, c);
    }

    // ---- phase 3: bias + residual + LN + relu (rows via perm) ----
    const float* bo = bout + (size_t)l * H;
    const float* gw = lnw + (size_t)l * H;
    const float* gb = lnb + (size_t)l * H;
    int col = w * 16 + ar;
    int rb = (lane >> 4) * 4;
    float v[4], y[4];
    int rowg[4];
    #pragma unroll
    for (int r = 0; r < 4; r++) {
        rowg[r] = perm[base + rb + r];
        v[r] = c[r] + bo[col] + h[(size_t)rowg[r] * H + col];
        float p1 = v[r];
        float p2 = v[r] * v[r];
        #pragma unroll
        for (int off = 1; off < 16; off <<= 1) {
            p1 += __shfl_xor(p1, off);
            p2 += __shfl_xor(p2, off);
        }
        if (ar == 0) { part1[w][rb + r] = p1; part2[w][rb + r] = p2; }
    }
    __syncthreads();
    #pragma unroll
    for (int r = 0; r < 4; r++) {
        int lr = rb + r;
        int row = rowg[r];
        float s1 = 0.f, s2 = 0.f;
        #pragma unroll
        for (int ww = 0; ww < 8; ww++) { s1 += part1[ww][lr]; s2 += part2[ww][lr]; }
        float m = s1 * (1.f / 128.f);
        float var = s2 * (1.f / 128.f) - m * m;
        float is = rsqrtf(var + EPS);
        y[r] = fmaxf((v[r] - m) * is * gw[col] + gb[col], 0.f);
        h[(size_t)row * H + col] = y[r];
        hbo[(size_t)row * H + col] = f2b(y[r]);
    }

    // ---- phase 4: next-layer alpha epilogue ----
    if (doAlpha) {
        #pragma unroll
        for (int comp = 0; comp < 8; comp++) {
            float vc = (comp < 4) ? vsn[comp * H + col] : vdn[(comp - 4) * H + col];
            float p[4];
            #pragma unroll
            for (int r = 0; r < 4; r++) p[r] = y[r] * vc;
            #pragma unroll
            for (int off = 1; off < 16; off <<= 1)
                #pragma unroll
                for (int r = 0; r < 4; r++) p[r] += __shfl_xor(p[r], off);
            if (ar == 0)
                #pragma unroll
                for (int r = 0; r < 4; r++) apart[w][comp][rb + r] = p[r];
        }
        __syncthreads();
        if (t < 128) {
            int lr = t >> 3, comp = t & 7;
            float s = 0.f;
            #pragma unroll
            for (int ww = 0; ww < 8; ww++) s += apart[ww][comp][lr];
            int node = perm[base + lr];
            if (comp < 4) asn[node * 4 + comp] = s;
            else          adn[node * 4 + comp - 4] = s;
        }
    }
}

// ---------------- pooling + MLPs ----------------
__global__ void k_pool(const float* __restrict__ h, const int* __restrict__ batch,
                       unsigned* __restrict__ g) {
    __shared__ float lm[G_GRAPHS][H];
    int t = threadIdx.x;
    #pragma unroll
    for (int i = 0; i < G_GRAPHS; i++) lm[i][t] = 0.f;
    int n0 = blockIdx.x * 100, n1 = n0 + 100;
    for (int n = n0; n < n1; n++) {
        int b = batch[n];
        lm[b][t] = fmaxf(lm[b][t], h[(size_t)n * H + t]);
    }
    #pragma unroll
    for (int i = 0; i < G_GRAPHS; i++)
        atomicMax(&g[i * H + t], __float_as_uint(lm[i][t]));
}

__global__ void k_mlp1(const unsigned* __restrict__ g, const float* __restrict__ Wp1,
                       const float* __restrict__ bp1, float* __restrict__ g1) {
    __shared__ float gs[H];
    int gr = blockIdx.x >> 2, ch = blockIdx.x & 3;
    int t = threadIdx.x;                        // 256
    if (t < H) gs[t] = __uint_as_float(g[gr * H + t]);
    __syncthreads();
    int col = ch * 256 + t;
    float acc = 0.f;
    for (int k = 0; k < H; k++) acc += gs[k] * Wp1[(size_t)k * OUT_DIM + col];
    acc += bp1[col];
    g1[(size_t)gr * OUT_DIM + col] = fmaxf(acc, 0.f);
}

__global__ void k_mlp2(const float* __restrict__ g1, const float* __restrict__ Wp2,
                       const float* __restrict__ bp2, float* __restrict__ out) {
    __shared__ float gs[OUT_DIM];
    __shared__ float part[4][64];
    int gr = blockIdx.x >> 4, ch = blockIdx.x & 15;
    int t = threadIdx.x;                        // 256
    int ci = t & 63, si = t >> 6;
    for (int i = t; i < OUT_DIM; i += 256) gs[i] = g1[(size_t)gr * OUT_DIM + i];
    __syncthreads();
    int col = ch * 64 + ci;
    float acc = 0.f;
    for (int k = si * 256; k < si * 256 + 256; k++)
        acc += gs[k] * Wp2[(size_t)k * OUT_DIM + col];
    part[si][ci] = acc;
    __syncthreads();
    if (si == 0) {
        float r = part[0][ci] + part[1][ci] + part[2][ci] + part[3][ci] + bp2[col];
        out[(size_t)gr * OUT_DIM + col] = r;
    }
}

// ---------------- launch ----------------
extern "C" void kernel_launch(void* const* d_in, const int* in_sizes, int n_in,
                              void* d_out, int out_size, void* d_ws, size_t ws_size,
                              hipStream_t stream) {
    const float* x       = (const float*)d_in[0];
    const int*   ei      = (const int*)d_in[1];     // int32
    const int*   batch   = (const int*)d_in[2];     // int32
    const float* W_in    = (const float*)d_in[3];
    const float* b_in    = (const float*)d_in[4];
    const float* ln_in_w = (const float*)d_in[5];
    const float* ln_in_b = (const float*)d_in[6];
    const float* Wsrc    = (const float*)d_in[7];
    const float* Wdst    = (const float*)d_in[8];
    const float* att_src = (const float*)d_in[9];
    const float* att_dst = (const float*)d_in[10];
    const float* Wout    = (const float*)d_in[11];
    const float* bout    = (const float*)d_in[12];
    const float* ln_w    = (const float*)d_in[13];
    const float* ln_b    = (const float*)d_in[14];
    const float* Wp1     = (const float*)d_in[15];
    const float* bp1     = (const float*)d_in[16];
    const float* Wp2     = (const float*)d_in[17];
    const float* bp2     = (const float*)d_in[18];

    char* w = (char*)d_ws;
    auto alloc = [&](size_t bytes) { void* p = w; w += (bytes + 255) & ~(size_t)255; return p; };
    float*     h     = (float*)alloc((size_t)N_NODES * H * 4);
    ushort_t*  hb0   = (ushort_t*)alloc((size_t)SPAD * H * 2);
    ushort_t*  hb1   = (ushort_t*)alloc((size_t)SPAD * H * 2);
    float*     as0   = (float*)alloc((size_t)SPAD * HEADS * 4);
    float*     ad0   = (float*)alloc((size_t)SPAD * HEADS * 4);
    float*     as1   = (float*)alloc((size_t)SPAD * HEADS * 4);
    float*     ad1   = (float*)alloc((size_t)SPAD * HEADS * 4);
    float*     vsrc  = (float*)alloc((size_t)L_LAYERS * HD * 4);
    float*     vdst  = (float*)alloc((size_t)L_LAYERS * HD * 4);
    float*     M     = (float*)alloc((size_t)L_LAYERS * HD * H * 4);
    ushort_t*  WpH   = (ushort_t*)alloc((size_t)L_LAYERS * 65536 * 2);
    ushort_t*  WpL   = (ushort_t*)alloc((size_t)L_LAYERS * 65536 * 2);
    ushort_t*  WpI   = (ushort_t*)alloc((size_t)D_IN * H * 2);
    int*       deg   = (int*)alloc((size_t)N_NODES * 4);
    int*       rs    = (int*)alloc((size_t)(N_NODES + 1) * 4);
    int*       cur   = (int*)alloc((size_t)N_NODES * 4);
    int*       elist = (int*)alloc((size_t)E2 * 4);
    int*       perm  = (int*)alloc((size_t)N_NODES * 4);
    int*       hist  = (int*)alloc(256 * 4);
    int*       binoff= (int*)alloc(256 * 4);
    int*       cur2  = (int*)alloc(256 * 4);
    unsigned*  g     = (unsigned*)alloc((size_t)G_GRAPHS * H * 4);
    float*     g1    = (float*)alloc((size_t)G_GRAPHS * OUT_DIM * 4);

    k_zero<<<40, 256, 0, stream>>>(deg, cur, g, hist, cur2);
    k_count<<<(E2 + 255) / 256, 256, 0, stream>>>(ei, deg);
    k_scan<<<1, 1024, 0, stream>>>(deg, rs);
    k_fill<<<(E2 + 255) / 256, 256, 0, stream>>>(ei, rs, cur, elist);
    k_hist<<<40, 256, 0, stream>>>(deg, hist);
    k_binscan<<<1, 256, 0, stream>>>(hist, binoff);
    k_scatter<<<40, 256, 0, stream>>>(deg, binoff, cur2, perm);
    k_vw<<<2048, 256, 0, stream>>>(Wsrc, Wdst, att_src, att_dst, vsrc, vdst);
    k_mm<<<256, 256, 0, stream>>>(Wsrc, Wout, M);
    k_pack_out2<<<4096, 256, 0, stream>>>(M, WpH, WpL);
    k_pack_win<<<128, 256, 0, stream>>>(W_in, WpI);
    k_in_mfma<<<N_NODES / 16, 256, 0, stream>>>(x, WpI, b_in, ln_in_w, ln_in_b,
                                                vsrc, vdst, as0, ad0, h, hb0);

    for (int l = 0; l < L_LAYERS; l++) {
        const ushort_t* hbi = (l & 1) ? hb1 : hb0;
        ushort_t*       hbo = (l & 1) ? hb0 : hb1;
        const float* aA = (l & 1) ? as1 : as0;
        const float* dA = (l & 1) ? ad1 : ad0;
        float* aB = (l & 1) ? as0 : as1;
        float* dB = (l & 1) ? ad0 : ad1;
        int ln = (l + 1 < L_LAYERS) ? (l + 1) : (L_LAYERS - 1);
        k_aggout<<<N_NODES / 16, 512, 0, stream>>>(
            hbi, (const float4*)aA, (const float4*)dA, rs, elist, perm, WpH, WpL,
            bout, ln_w, ln_b, vsrc + (size_t)ln * HD, vdst + (size_t)ln * HD,
            aB, dB, (l + 1 < L_LAYERS) ? 1 : 0, h, hbo, l);
    }

    k_pool<<<100, 128, 0, stream>>>(h, batch, g);
    k_mlp1<<<G_GRAPHS * 4, 256, 0, stream>>>(g, Wp1, bp1, g1);
    k_mlp2<<<G_GRAPHS * 16, 256, 0, stream>>>(g1, Wp2, bp2, (float*)d_out);
}

// Round 16
// 681.315 us; speedup vs baseline: 1.1706x; 1.1706x over previous
//
#include <hip/hip_runtime.h>
#include <hip/hip_bf16.h>

#define N_NODES 10000
#define E_EDGES 160000
#define E2 (E_EDGES + N_NODES)
#define D_IN 256
#define H 128
#define HEADS 4
#define HD 512
#define L_LAYERS 16
#define OUT_DIM 1024
#define G_GRAPHS 8
#define EPS 1e-5f
#define SPAD 10016

typedef unsigned short ushort_t;
typedef __attribute__((ext_vector_type(8))) short short8;
typedef __attribute__((ext_vector_type(4))) float f32x4;
typedef __attribute__((ext_vector_type(4))) unsigned u32x4;

__device__ __forceinline__ f32x4 mfma16(short8 a, short8 b, f32x4 c) {
    return __builtin_amdgcn_mfma_f32_16x16x32_bf16(a, b, c, 0, 0, 0);
}
__device__ __forceinline__ unsigned short f2b(float f) {   // f32 -> bf16 bits, RNE
    unsigned u = __float_as_uint(f);
    u += 0x7fffu + ((u >> 16) & 1u);
    return (unsigned short)(u >> 16);
}
__device__ __forceinline__ float b2f(unsigned short b) {
    return __uint_as_float((unsigned)b << 16);
}
__device__ __forceinline__ unsigned pk2(float lo, float hi) {  // 2xf32 -> packed bf16x2
    __hip_bfloat162 p = __float22bfloat162_rn(make_float2(lo, hi));
    return *(unsigned*)&p;
}

// ---------------- setup: CSR build (int32 edges) ----------------
__global__ void k_zero(int* deg, int* cur, unsigned* g) {
    int i = blockIdx.x * blockDim.x + threadIdx.x;
    if (i < N_NODES) { deg[i] = 0; cur[i] = 0; }
    if (i < G_GRAPHS * H) g[i] = 0u;
}

__global__ void k_count(const int* ei, int* deg) {
    int e = blockIdx.x * blockDim.x + threadIdx.x;
    if (e >= E2) return;
    int d = (e < E_EDGES) ? ei[E_EDGES + e] : (e - E_EDGES);
    atomicAdd(&deg[d], 1);
}

__global__ void k_scan(const int* deg, int* rs) {   // 1 block x 1024, 10 elems/thread
    __shared__ int s[1024];
    int t = threadIdx.x;
    int base = t * 10;
    int loc[10], run = 0;
    #pragma unroll
    for (int i = 0; i < 10; i++) {
        int idx = base + i;
        int v = (idx < N_NODES) ? deg[idx] : 0;
        loc[i] = run; run += v;
    }
    s[t] = run;
    __syncthreads();
    for (int off = 1; off < 1024; off <<= 1) {
        int xv = (t >= off) ? s[t - off] : 0;
        __syncthreads();
        s[t] += xv;
        __syncthreads();
    }
    int excl = s[t] - run;
    #pragma unroll
    for (int i = 0; i < 10; i++) {
        int idx = base + i;
        if (idx <= N_NODES) rs[idx] = excl + loc[i];
    }
}

__global__ void k_fill(const int* ei, const int* rs, int* cur, int* elist) {
    int e = blockIdx.x * blockDim.x + threadIdx.x;
    if (e >= E2) return;
    int s, d;
    if (e < E_EDGES) { s = ei[e]; d = ei[E_EDGES + e]; }
    else { s = d = e - E_EDGES; }
    int pos = atomicAdd(&cur[d], 1);
    elist[rs[d] + pos] = s;
}

// ---------------- weight preprocessing ----------------
// coalesced: one wave per (l, head, j); lanes split k; shfl tree-reduce
__global__ __launch_bounds__(256) void k_vw(const float* __restrict__ Wsrc,
        const float* __restrict__ Wdst, const float* __restrict__ att_src,
        const float* __restrict__ att_dst, float* __restrict__ vsrc,
        float* __restrict__ vdst) {
    int t = threadIdx.x, w = t >> 6, lane = t & 63;
    int unit = blockIdx.x * 4 + w;          // 8192 units
    int j = unit & 127, head = (unit >> 7) & 3, l = unit >> 9;
    int k2 = lane * 2;
    const float2 ws = *(const float2*)(Wsrc + (size_t)l * H * HD + (size_t)j * HD + head * 128 + k2);
    const float2 wd = *(const float2*)(Wdst + (size_t)l * H * HD + (size_t)j * HD + head * 128 + k2);
    const float2 as = *(const float2*)(att_src + (size_t)l * HEADS * H + head * 128 + k2);
    const float2 ad = *(const float2*)(att_dst + (size_t)l * HEADS * H + head * 128 + k2);
    float p = ws.x * as.x + ws.y * as.y;
    float q = wd.x * ad.x + wd.y * ad.y;
    #pragma unroll
    for (int off = 32; off > 0; off >>= 1) {
        p += __shfl_down(p, off);
        q += __shfl_down(q, off);
    }
    if (lane == 0) {
        vsrc[(size_t)l * HD + head * H + j] = p;
        vdst[(size_t)l * HD + head * H + j] = q;
    }
}

// M[l][h*128+k][o] = sum_c Wsrc[l][k][h*128+c] * Wout[l][h*128+c][o]
__global__ __launch_bounds__(256) void k_mm(const float* __restrict__ Wsrc,
        const float* __restrict__ Wout, float* __restrict__ M) {
    __shared__ float As[32][33];
    __shared__ float Bs[32][128];
    int bid = blockIdx.x;
    int q = bid & 3, hh = (bid >> 2) & 3, l = bid >> 4;
    int t = threadIdx.x;
    int ty = t >> 4, tx = t & 15;
    const float* WsB = Wsrc + (size_t)l * H * HD + (size_t)hh * 128;
    const float* WoB = Wout + (size_t)l * HD * H + (size_t)hh * 128 * H;
    float acc[2][8];
    #pragma unroll
    for (int r = 0; r < 2; r++)
        #pragma unroll
        for (int c = 0; c < 8; c++) acc[r][c] = 0.f;
    for (int kt = 0; kt < 4; kt++) {
        #pragma unroll
        for (int i = 0; i < 4; i++) {
            int lin = i * 256 + t;
            int rr = lin >> 5, cc = lin & 31;
            As[rr][cc] = WsB[(size_t)(q * 32 + rr) * HD + kt * 32 + cc];
        }
        #pragma unroll
        for (int i = 0; i < 16; i++) {
            int lin = i * 256 + t;
            int rr = lin >> 7, cc = lin & 127;
            Bs[rr][cc] = WoB[(size_t)(kt * 32 + rr) * H + cc];
        }
        __syncthreads();
        #pragma unroll
        for (int kk = 0; kk < 32; kk++) {
            float a0 = As[ty * 2][kk], a1 = As[ty * 2 + 1][kk];
            float4 b0 = *(const float4*)&Bs[kk][tx * 8];
            float4 b1 = *(const float4*)&Bs[kk][tx * 8 + 4];
            acc[0][0] += a0 * b0.x; acc[0][1] += a0 * b0.y;
            acc[0][2] += a0 * b0.z; acc[0][3] += a0 * b0.w;
            acc[0][4] += a0 * b1.x; acc[0][5] += a0 * b1.y;
            acc[0][6] += a0 * b1.z; acc[0][7] += a0 * b1.w;
            acc[1][0] += a1 * b0.x; acc[1][1] += a1 * b0.y;
            acc[1][2] += a1 * b0.z; acc[1][3] += a1 * b0.w;
            acc[1][4] += a1 * b1.x; acc[1][5] += a1 * b1.y;
            acc[1][6] += a1 * b1.z; acc[1][7] += a1 * b1.w;
        }
        __syncthreads();
    }
    #pragma unroll
    for (int r = 0; r < 2; r++)
        #pragma unroll
        for (int c = 0; c < 8; c++)
            M[(size_t)l * HD * H + (size_t)(hh * 128 + q * 32 + ty * 2 + r) * H + tx * 8 + c]
                = acc[r][c];
}

// pack M [L][512k][128col] f32 -> hi/lo B-frag layout [L][nt8][ks16][lane64][j8] bf16
__global__ void k_pack_out2(const float* M, ushort_t* Wh, ushort_t* Wl) {
    int idx = blockIdx.x * 256 + threadIdx.x;           // 16*65536 total
    int l = idx >> 16, rem = idx & 65535;
    int k = rem >> 7, col = rem & 127;
    float v = M[(size_t)l * HD * H + (size_t)k * H + col];
    unsigned short hi = f2b(v);
    unsigned short lo = f2b(v - b2f(hi));
    int nt = col >> 4, ks = k >> 5, lhi = (k >> 3) & 3, llo = col & 15, j = k & 7;
    size_t addr = (size_t)l * 65536 + (((size_t)(nt * 16 + ks) * 64) + lhi * 16 + llo) * 8 + j;
    Wh[addr] = hi;
    Wl[addr] = lo;
}

// pack W_in [256k][128col] f32 -> [nt8][ks8][lane64][j8] bf16
__global__ void k_pack_win(const float* W, ushort_t* Wp) {
    int idx = blockIdx.x * 256 + threadIdx.x;           // 32768 total
    int k = idx >> 7, col = idx & 127;
    float v = W[(size_t)k * H + col];
    int nt = col >> 4, ks = k >> 5, lhi = (k >> 3) & 3, llo = col & 15, j = k & 7;
    Wp[(((size_t)(nt * 8 + ks) * 64) + lhi * 16 + llo) * 8 + j] = f2b(v);
}

// ---------------- input layer: MFMA + LN + relu + layer-0 alpha epilogue ----------------
__global__ __launch_bounds__(256) void k_in_mfma(
        const float* __restrict__ x, const ushort_t* __restrict__ WpI,
        const float* __restrict__ b_in, const float* __restrict__ lnw,
        const float* __restrict__ lnb, const float* __restrict__ vs,
        const float* __restrict__ vd, float* __restrict__ as0, float* __restrict__ ad0,
        float* __restrict__ h, ushort_t* __restrict__ hb) {
    __shared__ float part1[4][16], part2[4][16];
    __shared__ float apart[4][8][16];
    int t = threadIdx.x, w = t >> 6, lane = t & 63;
    int row0 = blockIdx.x * 16;
    int ar = lane & 15, ac = (lane >> 4) * 8;
    short8 a[8];
    #pragma unroll
    for (int ks = 0; ks < 8; ks++) {
        const float* xp = x + (size_t)(row0 + ar) * D_IN + ks * 32 + ac;
        float4 xa = *(const float4*)xp;
        float4 xb = *(const float4*)(xp + 4);
        u32x4 u;
        u.x = pk2(xa.x, xa.y); u.y = pk2(xa.z, xa.w);
        u.z = pk2(xb.x, xb.y); u.w = pk2(xb.z, xb.w);
        a[ks] = *(short8*)&u;
    }
    const ushort_t* B0 = WpI + ((size_t)(w * 2 + 0) * 8) * 64 * 8;
    const ushort_t* B1 = WpI + ((size_t)(w * 2 + 1) * 8) * 64 * 8;
    f32x4 c0 = {0.f, 0.f, 0.f, 0.f}, c1 = {0.f, 0.f, 0.f, 0.f};
    #pragma unroll
    for (int ks = 0; ks < 8; ks++) {
        short8 b0 = *(const short8*)(B0 + ((size_t)ks * 64 + lane) * 8);
        short8 b1 = *(const short8*)(B1 + ((size_t)ks * 64 + lane) * 8);
        c0 = mfma16(a[ks], b0, c0);
        c1 = mfma16(a[ks], b1, c1);
    }
    int col0 = w * 32 + ar, col1 = w * 32 + 16 + ar;
    int rb = (lane >> 4) * 4;
    float v0[4], v1[4], y0[4], y1[4];
    #pragma unroll
    for (int r = 0; r < 4; r++) {
        v0[r] = c0[r] + b_in[col0];
        v1[r] = c1[r] + b_in[col1];
        float p1 = v0[r] + v1[r];
        float p2 = v0[r] * v0[r] + v1[r] * v1[r];
        #pragma unroll
        for (int off = 1; off < 16; off <<= 1) {
            p1 += __shfl_xor(p1, off);
            p2 += __shfl_xor(p2, off);
        }
        if (ar == 0) { part1[w][rb + r] = p1; part2[w][rb + r] = p2; }
    }
    __syncthreads();
    #pragma unroll
    for (int r = 0; r < 4; r++) {
        int lr = rb + r;
        int row = row0 + lr;
        float s1 = part1[0][lr] + part1[1][lr] + part1[2][lr] + part1[3][lr];
        float s2 = part2[0][lr] + part2[1][lr] + part2[2][lr] + part2[3][lr];
        float m = s1 * (1.f / 128.f);
        float var = s2 * (1.f / 128.f) - m * m;
        float is = rsqrtf(var + EPS);
        y0[r] = fmaxf((v0[r] - m) * is * lnw[col0] + lnb[col0], 0.f);
        y1[r] = fmaxf((v1[r] - m) * is * lnw[col1] + lnb[col1], 0.f);
        h[(size_t)row * H + col0] = y0[r];
        h[(size_t)row * H + col1] = y1[r];
        hb[(size_t)row * H + col0] = f2b(y0[r]);
        hb[(size_t)row * H + col1] = f2b(y1[r]);
    }
    // layer-0 alpha epilogue
    #pragma unroll
    for (int comp = 0; comp < 8; comp++) {
        float vc0 = (comp < 4) ? vs[comp * H + col0] : vd[(comp - 4) * H + col0];
        float vc1 = (comp < 4) ? vs[comp * H + col1] : vd[(comp - 4) * H + col1];
        float p[4];
        #pragma unroll
        for (int r = 0; r < 4; r++) p[r] = y0[r] * vc0 + y1[r] * vc1;
        #pragma unroll
        for (int off = 1; off < 16; off <<= 1)
            #pragma unroll
            for (int r = 0; r < 4; r++) p[r] += __shfl_xor(p[r], off);
        if (ar == 0)
            #pragma unroll
            for (int r = 0; r < 4; r++) apart[w][comp][rb + r] = p[r];
    }
    __syncthreads();
    if (t < 128) {
        int lr = t >> 3, comp = t & 7;
        float s = apart[0][comp][lr] + apart[1][comp][lr]
                + apart[2][comp][lr] + apart[3][comp][lr];
        int node = row0 + lr;
        if (comp < 4) as0[node * 4 + comp] = s;
        else          ad0[node * 4 + comp - 4] = s;
    }
}

// ---------------- fused T-agg + folded out-GEMM(hi+lo) + LN + next-layer alpha ----------------
// hb_in / hb_out are DISTINCT buffers (double-buffered across layers; no gather race)
#define ACC1(uv, wt) do { \
    acc[0] += (wt) * __uint_as_float((uv).x << 16); \
    acc[1] += (wt) * __uint_as_float((uv).x & 0xffff0000u); \
    acc[2] += (wt) * __uint_as_float((uv).y << 16); \
    acc[3] += (wt) * __uint_as_float((uv).y & 0xffff0000u); \
    acc[4] += (wt) * __uint_as_float((uv).z << 16); \
    acc[5] += (wt) * __uint_as_float((uv).z & 0xffff0000u); \
    acc[6] += (wt) * __uint_as_float((uv).w << 16); \
    acc[7] += (wt) * __uint_as_float((uv).w & 0xffff0000u); \
} while (0)

__global__ __launch_bounds__(512) void k_aggout(
        const ushort_t* __restrict__ hb, const float4* __restrict__ as4,
        const float4* __restrict__ ad4, const int* __restrict__ rs,
        const int* __restrict__ elist, const ushort_t* __restrict__ Wh,
        const ushort_t* __restrict__ Wl, const float* __restrict__ bout,
        const float* __restrict__ lnw, const float* __restrict__ lnb,
        const float* __restrict__ vsn, const float* __restrict__ vdn,
        float* __restrict__ asn, float* __restrict__ adn, int doAlpha,
        float* __restrict__ h, ushort_t* __restrict__ hbo, int l) {
    __shared__ ushort_t frag[16 * 64 * 8];      // 16KB
    __shared__ int sl[8][64];
    __shared__ float wl[8][64][4];
    __shared__ float part1[8][16], part2[8][16];
    __shared__ float apart[8][8][16];
    int t = threadIdx.x, w = t >> 6, lane = t & 63;
    int base = blockIdx.x * 16;
    int head = lane >> 4;
    int j8 = (lane & 15) * 8;

    // ---- phase 1: aggregate T for 2 nodes per wave ----
    for (int q = 0; q < 2; q++) {
        int r = w * 2 + q;
        int node = base + r;
        int start = rs[node], end = rs[node + 1];
        float4 adv = ad4[node];
        float acc[8];
        #pragma unroll
        for (int i = 0; i < 8; i++) acc[i] = 0.f;
        for (int c0 = start; c0 < end; c0 += 64) {
            int cnt = min(64, end - c0);
            if (lane < cnt) {
                int s = elist[c0 + lane];
                sl[w][lane] = s;
                float4 av = as4[s];
                float l0 = av.x + adv.x, l1 = av.y + adv.y, l2 = av.z + adv.z, l3 = av.w + adv.w;
                l0 = (l0 > 0.f) ? l0 : 0.2f * l0;
                l1 = (l1 > 0.f) ? l1 : 0.2f * l1;
                l2 = (l2 > 0.f) ? l2 : 0.2f * l2;
                l3 = (l3 > 0.f) ? l3 : 0.2f * l3;
                float mx = fmaxf(fmaxf(l0, l1), fmaxf(l2, l3));
                float e0 = expf(l0 - mx), e1 = expf(l1 - mx), e2 = expf(l2 - mx), e3 = expf(l3 - mx);
                float inv = 1.f / (e0 + e1 + e2 + e3);
                wl[w][lane][0] = e0 * inv;
                wl[w][lane][1] = e1 * inv;
                wl[w][lane][2] = e2 * inv;
                wl[w][lane][3] = e3 * inv;
            }
            __asm__ volatile("s_waitcnt lgkmcnt(0)" ::: "memory");
            int j = 0;
            if (cnt >= 4) {
                u32x4 b0, b1, b2, b3;
                float q0, q1, q2, q3;
                {
                    int s0 = sl[w][0], s1 = sl[w][1], s2 = sl[w][2], s3 = sl[w][3];
                    q0 = wl[w][0][head]; q1 = wl[w][1][head];
                    q2 = wl[w][2][head]; q3 = wl[w][3][head];
                    b0 = *(const u32x4*)(hb + (size_t)s0 * H + j8);
                    b1 = *(const u32x4*)(hb + (size_t)s1 * H + j8);
                    b2 = *(const u32x4*)(hb + (size_t)s2 * H + j8);
                    b3 = *(const u32x4*)(hb + (size_t)s3 * H + j8);
                }
                for (j = 4; j + 3 < cnt; j += 4) {
                    int s0 = sl[w][j], s1 = sl[w][j + 1], s2 = sl[w][j + 2], s3 = sl[w][j + 3];
                    u32x4 n0 = *(const u32x4*)(hb + (size_t)s0 * H + j8);
                    u32x4 n1 = *(const u32x4*)(hb + (size_t)s1 * H + j8);
                    u32x4 n2 = *(const u32x4*)(hb + (size_t)s2 * H + j8);
                    u32x4 n3 = *(const u32x4*)(hb + (size_t)s3 * H + j8);
                    float r0 = wl[w][j][head], r1 = wl[w][j + 1][head];
                    float r2 = wl[w][j + 2][head], r3 = wl[w][j + 3][head];
                    ACC1(b0, q0); ACC1(b1, q1); ACC1(b2, q2); ACC1(b3, q3);
                    b0 = n0; q0 = r0; b1 = n1; q1 = r1;
                    b2 = n2; q2 = r2; b3 = n3; q3 = r3;
                }
                ACC1(b0, q0); ACC1(b1, q1); ACC1(b2, q2); ACC1(b3, q3);
            }
            for (; j < cnt; j++) {
                int s = sl[w][j];
                float wt = wl[w][j][head];
                u32x4 uv = *(const u32x4*)(hb + (size_t)s * H + j8);
                ACC1(uv, wt);
            }
        }
        u32x4 o;
        o.x = pk2(acc[0], acc[1]);
        o.y = pk2(acc[2], acc[3]);
        o.z = pk2(acc[4], acc[5]);
        o.w = pk2(acc[6], acc[7]);
        int ksn = head * 4 + ((lane >> 2) & 3);
        int gidx = ((lane & 3) * 16 + r) * 16 + (ksn ^ r);
        *(u32x4*)((char*)frag + gidx * 16) = o;
    }
    __syncthreads();

    // ---- phase 2: out-GEMM 16x128, K=512, B = M_hi + M_lo ----
    const ushort_t* WLh = Wh + (size_t)l * 65536;
    const ushort_t* WLl = Wl + (size_t)l * 65536;
    short8 a[16];
    #pragma unroll
    for (int ks = 0; ks < 16; ks++) {
        int gidx = lane * 16 + (ks ^ (lane & 15));
        a[ks] = *(const short8*)((const char*)frag + gidx * 16);
    }
    int ar = lane & 15;
    f32x4 c = {0.f, 0.f, 0.f, 0.f};
    #pragma unroll
    for (int ks = 0; ks < 16; ks++) {
        short8 bh = *(const short8*)(WLh + ((size_t)(w * 16 + ks) * 64 + lane) * 8);
        c = mfma16(a[ks], bh, c);
    }
    #pragma unroll
    for (int ks = 0; ks < 16; ks++) {
        short8 bl = *(const short8*)(WLl + ((size_t)(w * 16 + ks) * 64 + lane) * 8);
        c = mfma16(a[ks], bl, c);
    }

    // ---- phase 3: bias + residual + LN + relu ----
    const float* bo = bout + (size_t)l * H;
    const float* gw = lnw + (size_t)l * H;
    const float* gb = lnb + (size_t)l * H;
    int col = w * 16 + ar;
    int rb = (lane >> 4) * 4;
    float v[4], y[4];
    #pragma unroll
    for (int r = 0; r < 4; r++) {
        int row = base + rb + r;
        v[r] = c[r] + bo[col] + h[(size_t)row * H + col];
        float p1 = v[r];
        float p2 = v[r] * v[r];
        #pragma unroll
        for (int off = 1; off < 16; off <<= 1) {
            p1 += __shfl_xor(p1, off);
            p2 += __shfl_xor(p2, off);
        }
        if (ar == 0) { part1[w][rb + r] = p1; part2[w][rb + r] = p2; }
    }
    __syncthreads();
    #pragma unroll
    for (int r = 0; r < 4; r++) {
        int lr = rb + r;
        int row = base + lr;
        float s1 = 0.f, s2 = 0.f;
        #pragma unroll
        for (int ww = 0; ww < 8; ww++) { s1 += part1[ww][lr]; s2 += part2[ww][lr]; }
        float m = s1 * (1.f / 128.f);
        float var = s2 * (1.f / 128.f) - m * m;
        float is = rsqrtf(var + EPS);
        y[r] = fmaxf((v[r] - m) * is * gw[col] + gb[col], 0.f);
        h[(size_t)row * H + col] = y[r];
        hbo[(size_t)row * H + col] = f2b(y[r]);
    }

    // ---- phase 4: next-layer alpha epilogue ----
    if (doAlpha) {
        #pragma unroll
        for (int comp = 0; comp < 8; comp++) {
            float vc = (comp < 4) ? vsn[comp * H + col] : vdn[(comp - 4) * H + col];
            float p[4];
            #pragma unroll
            for (int r = 0; r < 4; r++) p[r] = y[r] * vc;
            #pragma unroll
            for (int off = 1; off < 16; off <<= 1)
                #pragma unroll
                for (int r = 0; r < 4; r++) p[r] += __shfl_xor(p[r], off);
            if (ar == 0)
                #pragma unroll
                for (int r = 0; r < 4; r++) apart[w][comp][rb + r] = p[r];
        }
        __syncthreads();
        if (t < 128) {
            int lr = t >> 3, comp = t & 7;
            float s = 0.f;
            #pragma unroll
            for (int ww = 0; ww < 8; ww++) s += apart[ww][comp][lr];
            int node = base + lr;
            if (comp < 4) asn[node * 4 + comp] = s;
            else          adn[node * 4 + comp - 4] = s;
        }
    }
}

// ---------------- pooling + MLPs ----------------
__global__ void k_pool(const float* __restrict__ h, const int* __restrict__ batch,
                       unsigned* __restrict__ g) {
    __shared__ float lm[G_GRAPHS][H];
    int t = threadIdx.x;
    #pragma unroll
    for (int i = 0; i < G_GRAPHS; i++) lm[i][t] = 0.f;
    int n0 = blockIdx.x * 100, n1 = n0 + 100;
    for (int n = n0; n < n1; n++) {
        int b = batch[n];
        lm[b][t] = fmaxf(lm[b][t], h[(size_t)n * H + t]);
    }
    #pragma unroll
    for (int i = 0; i < G_GRAPHS; i++)
        atomicMax(&g[i * H + t], __float_as_uint(lm[i][t]));
}

__global__ void k_mlp1(const unsigned* __restrict__ g, const float* __restrict__ Wp1,
                       const float* __restrict__ bp1, float* __restrict__ g1) {
    __shared__ float gs[H];
    int gr = blockIdx.x >> 2, ch = blockIdx.x & 3;
    int t = threadIdx.x;                        // 256
    if (t < H) gs[t] = __uint_as_float(g[gr * H + t]);
    __syncthreads();
    int col = ch * 256 + t;
    float acc = 0.f;
    for (int k = 0; k < H; k++) acc += gs[k] * Wp1[(size_t)k * OUT_DIM + col];
    acc += bp1[col];
    g1[(size_t)gr * OUT_DIM + col] = fmaxf(acc, 0.f);
}

__global__ void k_mlp2(const float* __restrict__ g1, const float* __restrict__ Wp2,
                       const float* __restrict__ bp2, float* __restrict__ out) {
    __shared__ float gs[OUT_DIM];
    __shared__ float part[4][64];
    int gr = blockIdx.x >> 4, ch = blockIdx.x & 15;
    int t = threadIdx.x;                        // 256
    int ci = t & 63, si = t >> 6;
    for (int i = t; i < OUT_DIM; i += 256) gs[i] = g1[(size_t)gr * OUT_DIM + i];
    __syncthreads();
    int col = ch * 64 + ci;
    float acc = 0.f;
    for (int k = si * 256; k < si * 256 + 256; k++)
        acc += gs[k] * Wp2[(size_t)k * OUT_DIM + col];
    part[si][ci] = acc;
    __syncthreads();
    if (si == 0) {
        float r = part[0][ci] + part[1][ci] + part[2][ci] + part[3][ci] + bp2[col];
        out[(size_t)gr * OUT_DIM + col] = r;
    }
}

// ---------------- launch ----------------
extern "C" void kernel_launch(void* const* d_in, const int* in_sizes, int n_in,
                              void* d_out, int out_size, void* d_ws, size_t ws_size,
                              hipStream_t stream) {
    const float* x       = (const float*)d_in[0];
    const int*   ei      = (const int*)d_in[1];     // int32
    const int*   batch   = (const int*)d_in[2];     // int32
    const float* W_in    = (const float*)d_in[3];
    const float* b_in    = (const float*)d_in[4];
    const float* ln_in_w = (const float*)d_in[5];
    const float* ln_in_b = (const float*)d_in[6];
    const float* Wsrc    = (const float*)d_in[7];
    const float* Wdst    = (const float*)d_in[8];
    const float* att_src = (const float*)d_in[9];
    const float* att_dst = (const float*)d_in[10];
    const float* Wout    = (const float*)d_in[11];
    const float* bout    = (const float*)d_in[12];
    const float* ln_w    = (const float*)d_in[13];
    const float* ln_b    = (const float*)d_in[14];
    const float* Wp1     = (const float*)d_in[15];
    const float* bp1     = (const float*)d_in[16];
    const float* Wp2     = (const float*)d_in[17];
    const float* bp2     = (const float*)d_in[18];

    char* w = (char*)d_ws;
    auto alloc = [&](size_t bytes) { void* p = w; w += (bytes + 255) & ~(size_t)255; return p; };
    float*     h     = (float*)alloc((size_t)N_NODES * H * 4);
    ushort_t*  hb0   = (ushort_t*)alloc((size_t)SPAD * H * 2);
    ushort_t*  hb1   = (ushort_t*)alloc((size_t)SPAD * H * 2);
    float*     as0   = (float*)alloc((size_t)SPAD * HEADS * 4);
    float*     ad0   = (float*)alloc((size_t)SPAD * HEADS * 4);
    float*     as1   = (float*)alloc((size_t)SPAD * HEADS * 4);
    float*     ad1   = (float*)alloc((size_t)SPAD * HEADS * 4);
    float*     vsrc  = (float*)alloc((size_t)L_LAYERS * HD * 4);
    float*     vdst  = (float*)alloc((size_t)L_LAYERS * HD * 4);
    float*     M     = (float*)alloc((size_t)L_LAYERS * HD * H * 4);
    ushort_t*  WpH   = (ushort_t*)alloc((size_t)L_LAYERS * 65536 * 2);
    ushort_t*  WpL   = (ushort_t*)alloc((size_t)L_LAYERS * 65536 * 2);
    ushort_t*  WpI   = (ushort_t*)alloc((size_t)D_IN * H * 2);
    int*       deg   = (int*)alloc((size_t)N_NODES * 4);
    int*       rs    = (int*)alloc((size_t)(N_NODES + 1) * 4);
    int*       cur   = (int*)alloc((size_t)N_NODES * 4);
    int*       elist = (int*)alloc((size_t)E2 * 4);
    unsigned*  g     = (unsigned*)alloc((size_t)G_GRAPHS * H * 4);
    float*     g1    = (float*)alloc((size_t)G_GRAPHS * OUT_DIM * 4);

    k_zero<<<40, 256, 0, stream>>>(deg, cur, g);
    k_count<<<(E2 + 255) / 256, 256, 0, stream>>>(ei, deg);
    k_scan<<<1, 1024, 0, stream>>>(deg, rs);
    k_fill<<<(E2 + 255) / 256, 256, 0, stream>>>(ei, rs, cur, elist);
    k_vw<<<2048, 256, 0, stream>>>(Wsrc, Wdst, att_src, att_dst, vsrc, vdst);
    k_mm<<<256, 256, 0, stream>>>(Wsrc, Wout, M);
    k_pack_out2<<<4096, 256, 0, stream>>>(M, WpH, WpL);
    k_pack_win<<<128, 256, 0, stream>>>(W_in, WpI);
    k_in_mfma<<<N_NODES / 16, 256, 0, stream>>>(x, WpI, b_in, ln_in_w, ln_in_b,
                                                vsrc, vdst, as0, ad0, h, hb0);

    for (int l = 0; l < L_LAYERS; l++) {
        const ushort_t* hbi = (l & 1) ? hb1 : hb0;
        ushort_t*       hbo = (l & 1) ? hb0 : hb1;
        const float* aA = (l & 1) ? as1 : as0;
        const float* dA = (l & 1) ? ad1 : ad0;
        float* aB = (l & 1) ? as0 : as1;
        float* dB = (l & 1) ? ad0 : ad1;
        int ln = (l + 1 < L_LAYERS) ? (l + 1) : (L_LAYERS - 1);
        k_aggout<<<N_NODES / 16, 512, 0, stream>>>(
            hbi, (const float4*)aA, (const float4*)dA, rs, elist, WpH, WpL,
            bout, ln_w, ln_b, vsrc + (size_t)ln * HD, vdst + (size_t)ln * HD,
            aB, dB, (l + 1 < L_LAYERS) ? 1 : 0, h, hbo, l);
    }

    k_pool<<<100, 128, 0, stream>>>(h, batch, g);
    k_mlp1<<<G_GRAPHS * 4, 256, 0, stream>>>(g, Wp1, bp1, g1);
    k_mlp2<<<G_GRAPHS * 16, 256, 0, stream>>>(g1, Wp2, bp2, (float*)d_out);
}